// Round 2
// baseline (213.794 us; speedup 1.0000x reference)
//
#include <hip/hip_runtime.h>

typedef __bf16 bf16x8 __attribute__((ext_vector_type(8)));
typedef float f32x4 __attribute__((ext_vector_type(4)));
typedef unsigned short u16;

__device__ __forceinline__ u16 f2bf(float f) {
    union { float f; unsigned u; } v; v.f = f;
    unsigned r = (v.u + 0x7FFFu + ((v.u >> 16) & 1u)) >> 16;
    return (u16)r;
}

// ---- mask dtype detection + normalization: nm[i] in {0,1} -------------------
// If mask is int32[8192]: every word is 0 or 1.
// If mask is bool/uint8[8192]: words are 4 packed bytes -> values like 0x00010100 > 1.
// Reading 2048 words = 8KB is safe under both interpretations.
__global__ __launch_bounds__(256)
void normMask(const unsigned int* __restrict__ m, unsigned char* __restrict__ nm) {
    __shared__ int isByte;
    if (threadIdx.x == 0) isByte = 0;
    __syncthreads();
    int bad = 0;
    for (int i = threadIdx.x; i < 2048; i += 256) bad |= (m[i] > 1u);
    if (bad) atomicOr(&isByte, 1);
    __syncthreads();
    if (isByte) {
        const unsigned char* mb = (const unsigned char*)m;
        for (int i = threadIdx.x; i < 8192; i += 256) nm[i] = mb[i] ? 1 : 0;
    } else {
        for (int i = threadIdx.x; i < 8192; i += 256) nm[i] = (unsigned char)m[i];
    }
}

// ---------------- W transpose+convert: Wt[n,k] = bf16(W[k,n]), 3 mats concat ----
__global__ __launch_bounds__(256)
void transW(const float* __restrict__ Wq, const float* __restrict__ Wk,
            const float* __restrict__ Wv, u16* __restrict__ Wt) {
    __shared__ u16 tile[64][65];
    const float* W = blockIdx.z == 0 ? Wq : (blockIdx.z == 1 ? Wk : Wv);
    u16* out = Wt + (size_t)blockIdx.z * 1024 * 1024;
    int k0 = blockIdx.x * 64, n0 = blockIdx.y * 64;
    int t = threadIdx.x, cl = t & 63, rw = t >> 6;
    #pragma unroll
    for (int r = 0; r < 16; ++r) {
        int row = r * 4 + rw;
        tile[cl][row] = f2bf(W[(size_t)(k0 + row) * 1024 + n0 + cl]);
    }
    __syncthreads();
    #pragma unroll
    for (int r = 0; r < 16; ++r) {
        int row = r * 4 + rw;
        out[(size_t)(n0 + row) * 1024 + k0 + cl] = tile[row][cl];
    }
}

// ---------------- x -> bf16 --------------------------------------------------
__global__ __launch_bounds__(256)
void convX(const float* __restrict__ x, u16* __restrict__ xb) {
    const size_t n4 = (size_t)8192 * 1024 / 4;
    for (size_t i = (size_t)blockIdx.x * 256 + threadIdx.x; i < n4; i += (size_t)gridDim.x * 256) {
        float4 v = ((const float4*)x)[i];
        ushort4 o = make_ushort4(f2bf(v.x), f2bf(v.y), f2bf(v.z), f2bf(v.w));
        ((ushort4*)xb)[i] = o;
    }
}

// ---------------- V transpose: vt[b][d][s] = qkv[b*2048+s][2048+d] -----------
__global__ __launch_bounds__(256)
void transV(const u16* __restrict__ qkv, u16* __restrict__ vt) {
    __shared__ u16 tile[64][65];
    int b = blockIdx.z;
    int s0 = blockIdx.x * 64, d0 = blockIdx.y * 64;
    int t = threadIdx.x, cl = t & 63, rw = t >> 6;
    const u16* src = qkv + (size_t)b * 2048 * 3072 + 2048;
    #pragma unroll
    for (int r = 0; r < 16; ++r) {
        int row = r * 4 + rw;
        tile[cl][row] = src[(size_t)(s0 + row) * 3072 + d0 + cl];
    }
    __syncthreads();
    u16* dst = vt + (size_t)b * 1024 * 2048;
    #pragma unroll
    for (int r = 0; r < 16; ++r) {
        int row = r * 4 + rw;
        dst[(size_t)(d0 + row) * 2048 + s0 + cl] = tile[row][cl];
    }
}

// ---------------- GEMM C = A(MxK) * B(NxK)^T, bf16 in, 128x128 tile ----------
// Batched over blockIdx.z with element strides sA/sB/sC.
// OUTV==0: C bf16; OUTV==1/2: C fp32
template <int OUTV>
__global__ __launch_bounds__(256, 2)
void gemm_bt(const u16* __restrict__ A0, int lda, size_t sA,
             const u16* __restrict__ B0, int ldb, size_t sB,
             void* __restrict__ Cout, int ldc, size_t sC, int kdim) {
    __shared__ u16 lA[128 * 64];
    __shared__ u16 lB[128 * 64];
    const u16* A = A0 + (size_t)blockIdx.z * sA;
    const u16* B = B0 + (size_t)blockIdx.z * sB;
    const int t = threadIdx.x;
    const int w = t >> 6, l = t & 63;
    const int wr = w >> 1, wc = w & 1;
    const int brow = blockIdx.x * 128, bcol = blockIdx.y * 128;
    const int rt = l >> 3;          // staging row-within-8
    const int cb = (l & 7) * 8;     // staging col element

    auto ldsA3 = (__attribute__((address_space(3))) char*)lA;
    auto ldsB3 = (__attribute__((address_space(3))) char*)lB;

    f32x4 acc[4][4];
    #pragma unroll
    for (int m = 0; m < 4; ++m)
        #pragma unroll
        for (int n = 0; n < 4; ++n)
            acc[m][n] = (f32x4){0.f, 0.f, 0.f, 0.f};

    for (int k0 = 0; k0 < kdim; k0 += 64) {
        __syncthreads();
        #pragma unroll
        for (int p = 0; p < 4; ++p) {
            int chunk = p * 4 + w;          // 0..15, wave-uniform
            const u16* ga = A + (size_t)(brow + chunk * 8 + rt) * lda + k0 + cb;
            __builtin_amdgcn_global_load_lds(
                (const __attribute__((address_space(1))) void*)ga,
                (__attribute__((address_space(3))) void*)(ldsA3 + chunk * 1024), 16, 0, 0);
            const u16* gb = B + (size_t)(bcol + chunk * 8 + rt) * ldb + k0 + cb;
            __builtin_amdgcn_global_load_lds(
                (const __attribute__((address_space(1))) void*)gb,
                (__attribute__((address_space(3))) void*)(ldsB3 + chunk * 1024), 16, 0, 0);
        }
        __syncthreads();
        #pragma unroll
        for (int kk = 0; kk < 2; ++kk) {
            bf16x8 af[4], bfv[4];
            #pragma unroll
            for (int m = 0; m < 4; ++m)
                af[m] = *(const bf16x8*)&lA[(wr * 64 + m * 16 + (l & 15)) * 64 + kk * 32 + (l >> 4) * 8];
            #pragma unroll
            for (int n = 0; n < 4; ++n)
                bfv[n] = *(const bf16x8*)&lB[(wc * 64 + n * 16 + (l & 15)) * 64 + kk * 32 + (l >> 4) * 8];
            #pragma unroll
            for (int m = 0; m < 4; ++m)
                #pragma unroll
                for (int n = 0; n < 4; ++n)
                    acc[m][n] = __builtin_amdgcn_mfma_f32_16x16x32_bf16(af[m], bfv[n], acc[m][n], 0, 0, 0);
        }
    }

    const int lrow = (l >> 4) * 4, lcol = l & 15;
    #pragma unroll
    for (int m = 0; m < 4; ++m) {
        #pragma unroll
        for (int n = 0; n < 4; ++n) {
            int rr = brow + wr * 64 + m * 16 + lrow;
            int cc = bcol + wc * 64 + n * 16 + lcol;
            #pragma unroll
            for (int j = 0; j < 4; ++j) {
                if constexpr (OUTV == 0)
                    ((u16*)Cout)[(size_t)blockIdx.z * sC + (size_t)(rr + j) * ldc + cc] = f2bf(acc[m][n][j]);
                else
                    ((float*)Cout)[(size_t)blockIdx.z * sC + (size_t)(rr + j) * ldc + cc] = acc[m][n][j];
            }
        }
    }
}

// ---------------- row softmax: P[row,:] = softmax(scale * S[row,:]) ----------
__global__ __launch_bounds__(256)
void softmax_rows(const float* __restrict__ S0, size_t sS, u16* __restrict__ P0, size_t sP,
                  const unsigned char* __restrict__ nm, int bbase) {
    const int row = blockIdx.x, t = threadIdx.x;
    const int b = bbase + blockIdx.z;
    const float* S = S0 + (size_t)blockIdx.z * sS;
    u16* dst = P0 + (size_t)blockIdx.z * sP + (size_t)row * 2048;
    if (nm[b * 2048 + row] == 0) {
        // reference fp32 semantics: y-1e9 == -1e9 exactly -> uniform 1/2048
        ushort4 u = make_ushort4(0x3A00, 0x3A00, 0x3A00, 0x3A00);
        ((ushort4*)dst)[t] = u;
        ((ushort4*)dst)[t + 256] = u;
        return;
    }
    const float4* src = (const float4*)(S + (size_t)row * 2048);
    float4 a = src[t], c = src[t + 256];
    float v[8] = {a.x, a.y, a.z, a.w, c.x, c.y, c.z, c.w};
    float mx = -1e30f;
    #pragma unroll
    for (int i = 0; i < 8; ++i) { v[i] *= 0.03125f; mx = fmaxf(mx, v[i]); }
    #pragma unroll
    for (int o = 32; o > 0; o >>= 1) mx = fmaxf(mx, __shfl_xor(mx, o));
    __shared__ float redm[4], reds[4];
    if ((t & 63) == 0) redm[t >> 6] = mx;
    __syncthreads();
    mx = fmaxf(fmaxf(redm[0], redm[1]), fmaxf(redm[2], redm[3]));
    float s = 0.f;
    #pragma unroll
    for (int i = 0; i < 8; ++i) { v[i] = expf(v[i] - mx); s += v[i]; }
    #pragma unroll
    for (int o = 32; o > 0; o >>= 1) s += __shfl_xor(s, o);
    if ((t & 63) == 0) reds[t >> 6] = s;
    __syncthreads();
    s = (reds[0] + reds[1]) + (reds[2] + reds[3]);
    float inv = 1.0f / s;
    ushort4 o0 = make_ushort4(f2bf(v[0] * inv), f2bf(v[1] * inv), f2bf(v[2] * inv), f2bf(v[3] * inv));
    ushort4 o1 = make_ushort4(f2bf(v[4] * inv), f2bf(v[5] * inv), f2bf(v[6] * inv), f2bf(v[7] * inv));
    ((ushort4*)dst)[t] = o0;
    ((ushort4*)dst)[t + 256] = o1;
}

extern "C" void kernel_launch(void* const* d_in, const int* in_sizes, int n_in,
                              void* d_out, int out_size, void* d_ws, size_t ws_size,
                              hipStream_t stream) {
    const float* x  = (const float*)d_in[0];
    const float* Wq = (const float*)d_in[1];
    const float* Wk = (const float*)d_in[2];
    const float* Wv = (const float*)d_in[3];
    const unsigned int* mask = (const unsigned int*)d_in[4];
    float* out = (float*)d_out;

    // workspace layout
    char* p = (char*)d_ws;
    u16* Wt  = (u16*)p;  p += (size_t)3072 * 1024 * 2;        //  6 MB
    u16* xb  = (u16*)p;  p += (size_t)8192 * 1024 * 2;        // 16 MB
    u16* qkv = (u16*)p;  p += (size_t)8192 * 3072 * 2;        // 48 MB
    u16* vt  = (u16*)p;  p += (size_t)4 * 1024 * 2048 * 2;    // 16 MB
    char* base = p;
    const size_t sizeS = (size_t)2048 * 2048 * 4;             // 16 MB per batch
    const size_t sizeP = (size_t)2048 * 2048 * 2;             //  8 MB per batch
    // batched layout needs 4x(S+P) + nm; fallback needs 1x(S+P) + nm
    bool batched = ws_size >= (size_t)(base - (char*)d_ws) + 4 * (sizeS + sizeP) + 8192;

    float* S = (float*)base;
    u16* P;
    unsigned char* nm;
    if (batched) {
        P  = (u16*)(base + 4 * sizeS);
        nm = (unsigned char*)(base + 4 * (sizeS + sizeP));
    } else {
        P  = (u16*)(base + sizeS);
        nm = (unsigned char*)(base + sizeS + sizeP);
    }

    // 0) normalize mask (dtype-agnostic: int32 words vs packed bool bytes)
    normMask<<<1, 256, 0, stream>>>(mask, nm);
    // 1) Wt[n,k] = bf16(W[k,n]) for Wq|Wk|Wv
    transW<<<dim3(16, 16, 3), 256, 0, stream>>>(Wq, Wk, Wv, Wt);
    // 2) x -> bf16
    convX<<<2048, 256, 0, stream>>>(x, xb);
    // 3) qkv[r, 0:3072] = xb[r,:] @ Wt^T   (M=8192, N=3072, K=1024)
    gemm_bt<0><<<dim3(64, 24, 1), 256, 0, stream>>>(xb, 1024, 0, Wt, 1024, 0, qkv, 3072, 0, 1024);
    // 4) vt[b][d][s] = V
    transV<<<dim3(32, 16, 4), 256, 0, stream>>>(qkv, vt);
    // 5) scores -> softmax -> PV
    if (batched) {
        gemm_bt<1><<<dim3(16, 16, 4), 256, 0, stream>>>(
            qkv, 3072, (size_t)2048 * 3072, qkv + 1024, 3072, (size_t)2048 * 3072,
            S, 2048, (size_t)2048 * 2048, 1024);
        softmax_rows<<<dim3(2048, 1, 4), 256, 0, stream>>>(
            S, (size_t)2048 * 2048, P, (size_t)2048 * 2048, nm, 0);
        gemm_bt<2><<<dim3(16, 8, 4), 256, 0, stream>>>(
            P, 2048, (size_t)2048 * 2048, vt, 2048, (size_t)1024 * 2048,
            out, 1024, (size_t)2048 * 1024, 2048);
    } else {
        for (int b = 0; b < 4; ++b) {
            const u16* Qb = qkv + (size_t)b * 2048 * 3072;
            gemm_bt<1><<<dim3(16, 16, 1), 256, 0, stream>>>(
                Qb, 3072, 0, Qb + 1024, 3072, 0, S, 2048, 0, 1024);
            softmax_rows<<<dim3(2048, 1, 1), 256, 0, stream>>>(S, 0, P, 0, nm, b);
            gemm_bt<2><<<dim3(16, 8, 1), 256, 0, stream>>>(
                P, 2048, 0, vt + (size_t)b * 1024 * 2048, 2048, 0,
                out + (size_t)b * 2048 * 1024, 1024, 0, 2048);
        }
    }
}

// Round 3
// 211.015 us; speedup vs baseline: 1.0132x; 1.0132x over previous
//
#include <hip/hip_runtime.h>

typedef __bf16 bf16x8 __attribute__((ext_vector_type(8)));
typedef float f32x4 __attribute__((ext_vector_type(4)));
typedef unsigned short u16;

__device__ __forceinline__ u16 f2bf(float f) {
    union { float f; unsigned u; } v; v.f = f;
    unsigned r = (v.u + 0x7FFFu + ((v.u >> 16) & 1u)) >> 16;
    return (u16)r;
}

__device__ __forceinline__ void fence_bar() {
    asm volatile("" ::: "memory");
    __builtin_amdgcn_s_barrier();
    asm volatile("" ::: "memory");
}

// ---- mask dtype detection + normalization ----------------------------------
__global__ __launch_bounds__(256)
void normMask(const unsigned int* __restrict__ m, unsigned char* __restrict__ nm) {
    __shared__ int isByte;
    if (threadIdx.x == 0) isByte = 0;
    __syncthreads();
    int bad = 0;
    for (int i = threadIdx.x; i < 2048; i += 256) bad |= (m[i] > 1u);
    if (bad) atomicOr(&isByte, 1);
    __syncthreads();
    if (isByte) {
        const unsigned char* mb = (const unsigned char*)m;
        for (int i = threadIdx.x; i < 8192; i += 256) nm[i] = mb[i] ? 1 : 0;
    } else {
        for (int i = threadIdx.x; i < 8192; i += 256) nm[i] = (unsigned char)m[i];
    }
}

// ---------------- W transpose+convert ----------------------------------------
__global__ __launch_bounds__(256)
void transW(const float* __restrict__ Wq, const float* __restrict__ Wk,
            const float* __restrict__ Wv, u16* __restrict__ Wt) {
    __shared__ u16 tile[64][65];
    const float* W = blockIdx.z == 0 ? Wq : (blockIdx.z == 1 ? Wk : Wv);
    u16* out = Wt + (size_t)blockIdx.z * 1024 * 1024;
    int k0 = blockIdx.x * 64, n0 = blockIdx.y * 64;
    int t = threadIdx.x, cl = t & 63, rw = t >> 6;
    #pragma unroll
    for (int r = 0; r < 16; ++r) {
        int row = r * 4 + rw;
        tile[cl][row] = f2bf(W[(size_t)(k0 + row) * 1024 + n0 + cl]);
    }
    __syncthreads();
    #pragma unroll
    for (int r = 0; r < 16; ++r) {
        int row = r * 4 + rw;
        out[(size_t)(n0 + row) * 1024 + k0 + cl] = tile[row][cl];
    }
}

// ---------------- x -> bf16 --------------------------------------------------
__global__ __launch_bounds__(256)
void convX(const float* __restrict__ x, u16* __restrict__ xb) {
    const size_t n4 = (size_t)8192 * 1024 / 4;
    for (size_t i = (size_t)blockIdx.x * 256 + threadIdx.x; i < n4; i += (size_t)gridDim.x * 256) {
        float4 v = ((const float4*)x)[i];
        ushort4 o = make_ushort4(f2bf(v.x), f2bf(v.y), f2bf(v.z), f2bf(v.w));
        ((ushort4*)xb)[i] = o;
    }
}

// ---------------- V transpose ------------------------------------------------
__global__ __launch_bounds__(256)
void transV(const u16* __restrict__ qkv, u16* __restrict__ vt) {
    __shared__ u16 tile[64][65];
    int b = blockIdx.z;
    int s0 = blockIdx.x * 64, d0 = blockIdx.y * 64;
    int t = threadIdx.x, cl = t & 63, rw = t >> 6;
    const u16* src = qkv + (size_t)b * 2048 * 3072 + 2048;
    #pragma unroll
    for (int r = 0; r < 16; ++r) {
        int row = r * 4 + rw;
        tile[cl][row] = src[(size_t)(s0 + row) * 3072 + d0 + cl];
    }
    __syncthreads();
    u16* dst = vt + (size_t)b * 1024 * 2048;
    #pragma unroll
    for (int r = 0; r < 16; ++r) {
        int row = r * 4 + rw;
        dst[(size_t)(d0 + row) * 2048 + s0 + cl] = tile[row][cl];
    }
}

// ============ 8-phase 256x256 GEMM, counted vmcnt (T2-free K-half layout) =====
// C = A(MxK) x B(NxK)^T. 8 waves (2M x 4N), per-wave 128x64 out, BK=64.
// LDS [buf][kk][256 rows][32 k] per matrix; halves = K-halves (16KB, 2 gloads/thread).
// Schedule/tile t: PH1 reads (h0,kk0)+B(kk0), issues A1,B1(t+1);
//                  PH2 reads (h1,kk0); PH3 reads (h0,kk1)+B(kk1), issues A0(t+2);
//                  PH4 reads (h1,kk1), issues B0(t+2), vmcnt(4).
// Invariant entering tile t: tile t fully resident, A0,B0(t+1) in flight (4 loads).
template <int OUTV, int SWZ>
__global__ __launch_bounds__(512, 2)
void gemm8p(const u16* __restrict__ A_, int lda, size_t sA,
            const u16* __restrict__ B_, int ldb, size_t sB,
            void* __restrict__ Cout, int ldc, size_t sC,
            int kdim, int ntiles) {
    __shared__ u16 lds[65536];   // 128 KB: A [0,32768), B [32768,65536)
    const u16* A = A_ + (size_t)blockIdx.z * sA;
    const u16* B = B_ + (size_t)blockIdx.z * sB;

    int bid = blockIdx.x;
    if (SWZ) {
        int cpx = gridDim.x >> 3;           // gridDim.x % 8 == 0 required
        bid = (bid & 7) * cpx + (bid >> 3);
    }
    const int brow = (bid / ntiles) * 256, bcol = (bid % ntiles) * 256;

    const int t = threadIdx.x;
    const int w = t >> 6, l = t & 63;
    const int wr = w >> 2, wc = w & 3;

    // staging: row within 128-row issue block, 8-elem k chunk
    const size_t gA_th = (size_t)(brow + w * 16 + (l >> 2)) * lda + (l & 3) * 8;
    const size_t gB_th = (size_t)(bcol + w * 16 + (l >> 2)) * ldb + (l & 3) * 8;
    const int stTh = w * 512 + l * 8;       // lds elems within one half
    // frag-read bases (elems): row*32 + kchunk
    const int rA = (wr * 128 + (l & 15)) * 32 + (l >> 4) * 8;
    const int rB = 32768 + (wc * 64 + (l & 15)) * 32 + (l >> 4) * 8;

    auto lds3 = (__attribute__((address_space(3))) char*)lds;

    // issue one K-half (2 x global_load_lds of 16B per thread)
    #define ISSUE(matB, kk, tt, buf) do {                                          \
        const u16* gp0 = ((matB) ? B : A) + ((matB) ? gB_th : gA_th)               \
                         + (size_t)(tt) * 64 + (size_t)(kk) * 32;                  \
        const int ldm_ = (matB) ? ldb : lda;                                       \
        const int lbase_ = ((matB) ? 32768 : 0) + (buf) * 16384 + (kk) * 8192 + stTh; \
        __builtin_amdgcn_global_load_lds(                                          \
            (const __attribute__((address_space(1))) void*)gp0,                    \
            (__attribute__((address_space(3))) void*)(lds3 + 2 * lbase_), 16, 0, 0); \
        __builtin_amdgcn_global_load_lds(                                          \
            (const __attribute__((address_space(1))) void*)(gp0 + (size_t)128 * ldm_), \
            (__attribute__((address_space(3))) void*)(lds3 + 2 * (lbase_ + 4096)), 16, 0, 0); \
    } while (0)

    f32x4 acc[8][4];
    #pragma unroll
    for (int m = 0; m < 8; ++m)
        #pragma unroll
        for (int n = 0; n < 4; ++n)
            acc[m][n] = (f32x4){0.f, 0.f, 0.f, 0.f};

    const int NT = kdim >> 6;

    // prologue: tile0 all 4 halves + tile1 A0,B0
    ISSUE(0, 0, 0, 0); ISSUE(1, 0, 0, 0); ISSUE(0, 1, 0, 0); ISSUE(1, 1, 0, 0);
    if (NT > 1) {
        ISSUE(0, 0, 1, 1); ISSUE(1, 0, 1, 1);
        asm volatile("s_waitcnt vmcnt(4)" ::: "memory");
    } else {
        asm volatile("s_waitcnt vmcnt(0)" ::: "memory");
    }
    fence_bar();

    for (int tt = 0; tt < NT; ++tt) {
        const int c = tt & 1;
        const int ab = c * 16384;            // A buf base
        bf16x8 af[4], bfv[4];

        // ---- PH1: (h0, kk0) + B(kk0); issue A1,B1(t+1) ----
        #pragma unroll
        for (int m = 0; m < 4; ++m) af[m] = *(const bf16x8*)&lds[ab + rA + m * 512];
        #pragma unroll
        for (int n = 0; n < 4; ++n) bfv[n] = *(const bf16x8*)&lds[ab + rB + n * 512];
        if (tt + 1 < NT) { ISSUE(0, 1, tt + 1, c ^ 1); ISSUE(1, 1, tt + 1, c ^ 1); }
        fence_bar();
        __builtin_amdgcn_s_setprio(1);
        #pragma unroll
        for (int m = 0; m < 4; ++m)
            #pragma unroll
            for (int n = 0; n < 4; ++n)
                acc[m][n] = __builtin_amdgcn_mfma_f32_16x16x32_bf16(af[m], bfv[n], acc[m][n], 0, 0, 0);
        __builtin_amdgcn_s_setprio(0);
        fence_bar();

        // ---- PH2: (h1, kk0), reuse B(kk0) ----
        #pragma unroll
        for (int m = 0; m < 4; ++m) af[m] = *(const bf16x8*)&lds[ab + rA + (m + 4) * 512];
        fence_bar();
        __builtin_amdgcn_s_setprio(1);
        #pragma unroll
        for (int m = 0; m < 4; ++m)
            #pragma unroll
            for (int n = 0; n < 4; ++n)
                acc[m + 4][n] = __builtin_amdgcn_mfma_f32_16x16x32_bf16(af[m], bfv[n], acc[m + 4][n], 0, 0, 0);
        __builtin_amdgcn_s_setprio(0);
        fence_bar();

        // ---- PH3: (h0, kk1) + B(kk1); issue A0(t+2) into freed kk0 of buf c ----
        #pragma unroll
        for (int m = 0; m < 4; ++m) af[m] = *(const bf16x8*)&lds[ab + 8192 + rA + m * 512];
        #pragma unroll
        for (int n = 0; n < 4; ++n) bfv[n] = *(const bf16x8*)&lds[ab + 8192 + rB + n * 512];
        if (tt + 2 < NT) ISSUE(0, 0, tt + 2, c);
        fence_bar();
        __builtin_amdgcn_s_setprio(1);
        #pragma unroll
        for (int m = 0; m < 4; ++m)
            #pragma unroll
            for (int n = 0; n < 4; ++n)
                acc[m][n] = __builtin_amdgcn_mfma_f32_16x16x32_bf16(af[m], bfv[n], acc[m][n], 0, 0, 0);
        __builtin_amdgcn_s_setprio(0);
        fence_bar();

        // ---- PH4: (h1, kk1); issue B0(t+2); counted wait ----
        #pragma unroll
        for (int m = 0; m < 4; ++m) af[m] = *(const bf16x8*)&lds[ab + 8192 + rA + (m + 4) * 512];
        if (tt + 2 < NT) ISSUE(1, 0, tt + 2, c);
        fence_bar();
        __builtin_amdgcn_s_setprio(1);
        #pragma unroll
        for (int m = 0; m < 4; ++m)
            #pragma unroll
            for (int n = 0; n < 4; ++n)
                acc[m + 4][n] = __builtin_amdgcn_mfma_f32_16x16x32_bf16(af[m], bfv[n], acc[m + 4][n], 0, 0, 0);
        __builtin_amdgcn_s_setprio(0);
        if (tt + 2 < NT) asm volatile("s_waitcnt vmcnt(4)" ::: "memory");
        else             asm volatile("s_waitcnt vmcnt(0)" ::: "memory");
        fence_bar();
    }
    #undef ISSUE

    // epilogue: C[row=brow+wr*128+m*16+(l>>4)*4+j][col=bcol+wc*64+n*16+(l&15)]
    const int lr = (l >> 4) * 4, lc = l & 15;
    #pragma unroll
    for (int m = 0; m < 8; ++m) {
        #pragma unroll
        for (int n = 0; n < 4; ++n) {
            int rr = brow + wr * 128 + m * 16 + lr;
            int cc = bcol + wc * 64 + n * 16 + lc;
            #pragma unroll
            for (int j = 0; j < 4; ++j) {
                if constexpr (OUTV == 0)
                    ((u16*)Cout)[(size_t)blockIdx.z * sC + (size_t)(rr + j) * ldc + cc] = f2bf(acc[m][n][j]);
                else
                    ((float*)Cout)[(size_t)blockIdx.z * sC + (size_t)(rr + j) * ldc + cc] = acc[m][n][j];
            }
        }
    }
}

// ---------------- 2-phase 128x128 GEMM (kept for PV + fallback) --------------
template <int OUTV>
__global__ __launch_bounds__(256, 2)
void gemm_bt(const u16* __restrict__ A0, int lda, size_t sA,
             const u16* __restrict__ B0, int ldb, size_t sB,
             void* __restrict__ Cout, int ldc, size_t sC, int kdim) {
    __shared__ u16 lA[128 * 64];
    __shared__ u16 lB[128 * 64];
    const u16* A = A0 + (size_t)blockIdx.z * sA;
    const u16* B = B0 + (size_t)blockIdx.z * sB;
    const int t = threadIdx.x;
    const int w = t >> 6, l = t & 63;
    const int wr = w >> 1, wc = w & 1;
    const int brow = blockIdx.x * 128, bcol = blockIdx.y * 128;
    const int rt = l >> 3;
    const int cb = (l & 7) * 8;

    auto ldsA3 = (__attribute__((address_space(3))) char*)lA;
    auto ldsB3 = (__attribute__((address_space(3))) char*)lB;

    f32x4 acc[4][4];
    #pragma unroll
    for (int m = 0; m < 4; ++m)
        #pragma unroll
        for (int n = 0; n < 4; ++n)
            acc[m][n] = (f32x4){0.f, 0.f, 0.f, 0.f};

    for (int k0 = 0; k0 < kdim; k0 += 64) {
        __syncthreads();
        #pragma unroll
        for (int p = 0; p < 4; ++p) {
            int chunk = p * 4 + w;
            const u16* ga = A + (size_t)(brow + chunk * 8 + rt) * lda + k0 + cb;
            __builtin_amdgcn_global_load_lds(
                (const __attribute__((address_space(1))) void*)ga,
                (__attribute__((address_space(3))) void*)(ldsA3 + chunk * 1024), 16, 0, 0);
            const u16* gb = B + (size_t)(bcol + chunk * 8 + rt) * ldb + k0 + cb;
            __builtin_amdgcn_global_load_lds(
                (const __attribute__((address_space(1))) void*)gb,
                (__attribute__((address_space(3))) void*)(ldsB3 + chunk * 1024), 16, 0, 0);
        }
        __syncthreads();
        #pragma unroll
        for (int kk = 0; kk < 2; ++kk) {
            bf16x8 af[4], bfv[4];
            #pragma unroll
            for (int m = 0; m < 4; ++m)
                af[m] = *(const bf16x8*)&lA[(wr * 64 + m * 16 + (l & 15)) * 64 + kk * 32 + (l >> 4) * 8];
            #pragma unroll
            for (int n = 0; n < 4; ++n)
                bfv[n] = *(const bf16x8*)&lB[(wc * 64 + n * 16 + (l & 15)) * 64 + kk * 32 + (l >> 4) * 8];
            #pragma unroll
            for (int m = 0; m < 4; ++m)
                #pragma unroll
                for (int n = 0; n < 4; ++n)
                    acc[m][n] = __builtin_amdgcn_mfma_f32_16x16x32_bf16(af[m], bfv[n], acc[m][n], 0, 0, 0);
        }
    }

    const int lrow = (l >> 4) * 4, lcol = l & 15;
    #pragma unroll
    for (int m = 0; m < 4; ++m) {
        #pragma unroll
        for (int n = 0; n < 4; ++n) {
            int rr = brow + wr * 64 + m * 16 + lrow;
            int cc = bcol + wc * 64 + n * 16 + lcol;
            #pragma unroll
            for (int j = 0; j < 4; ++j) {
                if constexpr (OUTV == 0)
                    ((u16*)Cout)[(size_t)blockIdx.z * sC + (size_t)(rr + j) * ldc + cc] = f2bf(acc[m][n][j]);
                else
                    ((float*)Cout)[(size_t)blockIdx.z * sC + (size_t)(rr + j) * ldc + cc] = acc[m][n][j];
            }
        }
    }
}

// ---------------- row softmax ------------------------------------------------
__global__ __launch_bounds__(256)
void softmax_rows(const float* __restrict__ S0, size_t sS, u16* __restrict__ P0, size_t sP,
                  const unsigned char* __restrict__ nm, int bbase) {
    const int row = blockIdx.x, t = threadIdx.x;
    const int b = bbase + blockIdx.z;
    const float* S = S0 + (size_t)blockIdx.z * sS;
    u16* dst = P0 + (size_t)blockIdx.z * sP + (size_t)row * 2048;
    if (nm[b * 2048 + row] == 0) {
        ushort4 u = make_ushort4(0x3A00, 0x3A00, 0x3A00, 0x3A00);
        ((ushort4*)dst)[t] = u;
        ((ushort4*)dst)[t + 256] = u;
        return;
    }
    const float4* src = (const float4*)(S + (size_t)row * 2048);
    float4 a = src[t], c = src[t + 256];
    float v[8] = {a.x, a.y, a.z, a.w, c.x, c.y, c.z, c.w};
    float mx = -1e30f;
    #pragma unroll
    for (int i = 0; i < 8; ++i) { v[i] *= 0.03125f; mx = fmaxf(mx, v[i]); }
    #pragma unroll
    for (int o = 32; o > 0; o >>= 1) mx = fmaxf(mx, __shfl_xor(mx, o));
    __shared__ float redm[4], reds[4];
    if ((t & 63) == 0) redm[t >> 6] = mx;
    __syncthreads();
    mx = fmaxf(fmaxf(redm[0], redm[1]), fmaxf(redm[2], redm[3]));
    float s = 0.f;
    #pragma unroll
    for (int i = 0; i < 8; ++i) { v[i] = expf(v[i] - mx); s += v[i]; }
    #pragma unroll
    for (int o = 32; o > 0; o >>= 1) s += __shfl_xor(s, o);
    if ((t & 63) == 0) reds[t >> 6] = s;
    __syncthreads();
    s = (reds[0] + reds[1]) + (reds[2] + reds[3]);
    float inv = 1.0f / s;
    ushort4 o0 = make_ushort4(f2bf(v[0] * inv), f2bf(v[1] * inv), f2bf(v[2] * inv), f2bf(v[3] * inv));
    ushort4 o1 = make_ushort4(f2bf(v[4] * inv), f2bf(v[5] * inv), f2bf(v[6] * inv), f2bf(v[7] * inv));
    ((ushort4*)dst)[t] = o0;
    ((ushort4*)dst)[t + 256] = o1;
}

extern "C" void kernel_launch(void* const* d_in, const int* in_sizes, int n_in,
                              void* d_out, int out_size, void* d_ws, size_t ws_size,
                              hipStream_t stream) {
    const float* x  = (const float*)d_in[0];
    const float* Wq = (const float*)d_in[1];
    const float* Wk = (const float*)d_in[2];
    const float* Wv = (const float*)d_in[3];
    const unsigned int* mask = (const unsigned int*)d_in[4];
    float* out = (float*)d_out;

    char* p = (char*)d_ws;
    u16* Wt  = (u16*)p;  p += (size_t)3072 * 1024 * 2;
    u16* xb  = (u16*)p;  p += (size_t)8192 * 1024 * 2;
    u16* qkv = (u16*)p;  p += (size_t)8192 * 3072 * 2;
    u16* vt  = (u16*)p;  p += (size_t)4 * 1024 * 2048 * 2;
    char* base = p;
    const size_t sizeS = (size_t)2048 * 2048 * 4;
    const size_t sizeP = (size_t)2048 * 2048 * 2;
    bool batched = ws_size >= (size_t)(base - (char*)d_ws) + 4 * (sizeS + sizeP) + 8192;

    float* S = (float*)base;
    u16* P;
    unsigned char* nm;
    if (batched) {
        P  = (u16*)(base + 4 * sizeS);
        nm = (unsigned char*)(base + 4 * (sizeS + sizeP));
    } else {
        P  = (u16*)(base + sizeS);
        nm = (unsigned char*)(base + sizeS + sizeP);
    }

    normMask<<<1, 256, 0, stream>>>(mask, nm);
    transW<<<dim3(16, 16, 3), 256, 0, stream>>>(Wq, Wk, Wv, Wt);
    convX<<<2048, 256, 0, stream>>>(x, xb);
    // QKV: M=8192 N=3072 K=1024 -> 32x12=384 tiles, XCD-swizzled
    gemm8p<0, 1><<<dim3(384, 1, 1), 512, 0, stream>>>(
        xb, 1024, 0, Wt, 1024, 0, qkv, 3072, 0, 1024, 12);
    transV<<<dim3(32, 16, 4), 256, 0, stream>>>(qkv, vt);

    if (batched) {
        // scores: per batch M=N=2048 K=1024 -> 8x8 tiles, z=4 (256 blocks = 1/CU)
        gemm8p<1, 0><<<dim3(64, 1, 4), 512, 0, stream>>>(
            qkv, 3072, (size_t)2048 * 3072, qkv + 1024, 3072, (size_t)2048 * 3072,
            S, 2048, (size_t)2048 * 2048, 1024, 8);
        softmax_rows<<<dim3(2048, 1, 4), 256, 0, stream>>>(
            S, (size_t)2048 * 2048, P, (size_t)2048 * 2048, nm, 0);
        gemm_bt<2><<<dim3(16, 8, 4), 256, 0, stream>>>(
            P, 2048, (size_t)2048 * 2048, vt, 2048, (size_t)1024 * 2048,
            out, 1024, (size_t)2048 * 1024, 2048);
    } else {
        for (int b = 0; b < 4; ++b) {
            const u16* Qb = qkv + (size_t)b * 2048 * 3072;
            gemm8p<1, 0><<<dim3(64, 1, 1), 512, 0, stream>>>(
                Qb, 3072, 0, Qb + 1024, 3072, 0, S, 2048, 0, 1024, 8);
            softmax_rows<<<dim3(2048, 1, 1), 256, 0, stream>>>(S, 0, P, 0, nm, b);
            gemm_bt<2><<<dim3(16, 8, 1), 256, 0, stream>>>(
                P, 2048, 0, vt + (size_t)b * 1024 * 2048, 2048, 0,
                out + (size_t)b * 2048 * 1024, 1024, 0, 2048);
        }
    }
}

// Round 4
// 201.314 us; speedup vs baseline: 1.0620x; 1.0482x over previous
//
#include <hip/hip_runtime.h>

typedef __bf16 bf16x8 __attribute__((ext_vector_type(8)));
typedef float f32x4 __attribute__((ext_vector_type(4)));
typedef unsigned short u16;

__device__ __forceinline__ u16 f2bf(float f) {
    union { float f; unsigned u; } v; v.f = f;
    unsigned r = (v.u + 0x7FFFu + ((v.u >> 16) & 1u)) >> 16;
    return (u16)r;
}

__device__ __forceinline__ void fence_bar() {
    asm volatile("" ::: "memory");
    __builtin_amdgcn_s_barrier();
    asm volatile("" ::: "memory");
}

// ---- mask dtype detection + normalization ----------------------------------
__global__ __launch_bounds__(256)
void normMask(const unsigned int* __restrict__ m, unsigned char* __restrict__ nm) {
    __shared__ int isByte;
    if (threadIdx.x == 0) isByte = 0;
    __syncthreads();
    int bad = 0;
    for (int i = threadIdx.x; i < 2048; i += 256) bad |= (m[i] > 1u);
    if (bad) atomicOr(&isByte, 1);
    __syncthreads();
    if (isByte) {
        const unsigned char* mb = (const unsigned char*)m;
        for (int i = threadIdx.x; i < 8192; i += 256) nm[i] = mb[i] ? 1 : 0;
    } else {
        for (int i = threadIdx.x; i < 8192; i += 256) nm[i] = (unsigned char)m[i];
    }
}

// ---------------- W transpose+convert ----------------------------------------
__global__ __launch_bounds__(256)
void transW(const float* __restrict__ Wq, const float* __restrict__ Wk,
            const float* __restrict__ Wv, u16* __restrict__ Wt) {
    __shared__ u16 tile[64][65];
    const float* W = blockIdx.z == 0 ? Wq : (blockIdx.z == 1 ? Wk : Wv);
    u16* out = Wt + (size_t)blockIdx.z * 1024 * 1024;
    int k0 = blockIdx.x * 64, n0 = blockIdx.y * 64;
    int t = threadIdx.x, cl = t & 63, rw = t >> 6;
    #pragma unroll
    for (int r = 0; r < 16; ++r) {
        int row = r * 4 + rw;
        tile[cl][row] = f2bf(W[(size_t)(k0 + row) * 1024 + n0 + cl]);
    }
    __syncthreads();
    #pragma unroll
    for (int r = 0; r < 16; ++r) {
        int row = r * 4 + rw;
        out[(size_t)(n0 + row) * 1024 + k0 + cl] = tile[row][cl];
    }
}

// ---------------- x -> bf16 --------------------------------------------------
__global__ __launch_bounds__(256)
void convX(const float* __restrict__ x, u16* __restrict__ xb) {
    const size_t n4 = (size_t)8192 * 1024 / 4;
    for (size_t i = (size_t)blockIdx.x * 256 + threadIdx.x; i < n4; i += (size_t)gridDim.x * 256) {
        float4 v = ((const float4*)x)[i];
        ushort4 o = make_ushort4(f2bf(v.x), f2bf(v.y), f2bf(v.z), f2bf(v.w));
        ((ushort4*)xb)[i] = o;
    }
}

// ---------------- V transpose ------------------------------------------------
__global__ __launch_bounds__(256)
void transV(const u16* __restrict__ qkv, u16* __restrict__ vt) {
    __shared__ u16 tile[64][65];
    int b = blockIdx.z;
    int s0 = blockIdx.x * 64, d0 = blockIdx.y * 64;
    int t = threadIdx.x, cl = t & 63, rw = t >> 6;
    const u16* src = qkv + (size_t)b * 2048 * 3072 + 2048;
    #pragma unroll
    for (int r = 0; r < 16; ++r) {
        int row = r * 4 + rw;
        tile[cl][row] = src[(size_t)(s0 + row) * 3072 + d0 + cl];
    }
    __syncthreads();
    u16* dst = vt + (size_t)b * 1024 * 2048;
    #pragma unroll
    for (int r = 0; r < 16; ++r) {
        int row = r * 4 + rw;
        dst[(size_t)(d0 + row) * 2048 + s0 + cl] = tile[row][cl];
    }
}

// ============ 8-phase 256x256 GEMM + T2 swizzle (m201-faithful layout) ========
// C = A(MxK) x B(NxK)^T. 8 waves (2M x 4N), per-wave 128x64 out, BK=64.
// LDS per matrix: [buf2][256 rows][64 k] u16, 128B rows, 8x16B slots.
// T2: LDS[r][slot s] holds G[r][s ^ (r&7)] (linear lane-dest + pre-swizzled
// per-lane global src; ds_read applies same XOR -> involution, rule #21).
// Staging unit = 64 rows x 64 k (1 gload/thread). 8 units/K-tile.
// Stream/tile t: PH1 issues B-q0,q1(t+1) + vmcnt(2); PH2 issues B-q2,q3;
// PH3 issues A-q0,q2; PH4 issues A-q1,q3 + vmcnt(2).
// Retire proof: PH4's vmcnt(2) retires B-all+A-q0,q2(t+1) (needed PH1');
// PH1''s vmcnt(2) retires A-q1,q3 (needed PH2'). Never drains to 0 mid-loop.
template <int OUTV>
__global__ __launch_bounds__(512, 2)
void gemm8p(const u16* __restrict__ A_, int lda, size_t sA,
            const u16* __restrict__ B_, int ldb, size_t sB,
            void* __restrict__ Cout, int ldc, size_t sC,
            int kdim, int ntiles) {
    __shared__ u16 lds[65536];   // A: [0,32768) ; B: [32768,65536)
    const u16* A = A_ + (size_t)blockIdx.z * sA;
    const u16* B = B_ + (size_t)blockIdx.z * sB;

    const int bid = blockIdx.x;
    const int brow = (bid / ntiles) * 256, bcol = (bid % ntiles) * 256;
    const int t = threadIdx.x;
    const int w = t >> 6, l = t & 63;
    const int wr = w >> 2, wc = w & 3;

    // staging geometry: thread t covers row q*64 + (t>>3), swizzled slot
    const int srow = t >> 3;                      // 0..63
    const int sslot = (t & 7) ^ (srow & 7);       // global slot to fetch
    // frag-read bases (elems); chunk XOR per T2
    const int aBase = (wr * 128 + (l & 15)) * 64;
    const int bBase = 32768 + (wc * 64 + (l & 15)) * 64;
    const int cx0 = (((l >> 4)) ^ (l & 7)) * 8;       // kk0 chunk offset
    const int cx1 = (((l >> 4) + 4) ^ (l & 7)) * 8;   // kk1 chunk offset

    auto lds3 = (__attribute__((address_space(3))) char*)lds;

    // stage one 64-row unit of tile tt into buf
    #define ISSUE(matB, q, tt, buf) do {                                           \
        const u16* gsrc = ((matB) ? B : A)                                         \
            + (size_t)(((matB) ? bcol : brow) + (q) * 64 + srow) * ((matB) ? ldb : lda) \
            + (size_t)(tt) * 64 + sslot * 8;                                       \
        const int dst_ = ((matB) ? 32768 : 0) + (buf) * 16384 + (q) * 4096 + t * 8; \
        __builtin_amdgcn_global_load_lds(                                          \
            (const __attribute__((address_space(1))) void*)gsrc,                   \
            (__attribute__((address_space(3))) void*)(lds3 + 2 * dst_), 16, 0, 0); \
    } while (0)

    f32x4 acc[8][4];
    #pragma unroll
    for (int m = 0; m < 8; ++m)
        #pragma unroll
        for (int n = 0; n < 4; ++n)
            acc[m][n] = (f32x4){0.f, 0.f, 0.f, 0.f};

    const int NT = kdim >> 6;

    // prologue: tile0 all 8 units; last two issued = A-q1,q3 (needed PH2 only)
    ISSUE(1, 0, 0, 0); ISSUE(1, 1, 0, 0); ISSUE(1, 2, 0, 0); ISSUE(1, 3, 0, 0);
    ISSUE(0, 0, 0, 0); ISSUE(0, 2, 0, 0); ISSUE(0, 1, 0, 0); ISSUE(0, 3, 0, 0);
    asm volatile("s_waitcnt vmcnt(2)" ::: "memory");
    fence_bar();

    for (int tt = 0; tt < NT; ++tt) {
        const int c = tt & 1;
        const int ab = c * 16384;
        const int nb = c ^ 1;
        const bool pf = (tt + 1 < NT);
        bf16x8 af[4], bfv[4];

        // ---- PH1: A(m0-3,kk0) + B(n0-3,kk0); issue B-q0,q1(t+1); vmcnt(2) ----
        #pragma unroll
        for (int m = 0; m < 4; ++m) af[m] = *(const bf16x8*)&lds[ab + aBase + m * 1024 + cx0];
        #pragma unroll
        for (int n = 0; n < 4; ++n) bfv[n] = *(const bf16x8*)&lds[ab + bBase + n * 1024 + cx0];
        if (pf) {
            ISSUE(1, 0, tt + 1, nb); ISSUE(1, 1, tt + 1, nb);
            asm volatile("s_waitcnt vmcnt(2)" ::: "memory");
        } else {
            asm volatile("s_waitcnt vmcnt(0)" ::: "memory");
        }
        fence_bar();
        __builtin_amdgcn_s_setprio(1);
        #pragma unroll
        for (int m = 0; m < 4; ++m)
            #pragma unroll
            for (int n = 0; n < 4; ++n)
                acc[m][n] = __builtin_amdgcn_mfma_f32_16x16x32_bf16(af[m], bfv[n], acc[m][n], 0, 0, 0);
        __builtin_amdgcn_s_setprio(0);
        fence_bar();

        // ---- PH2: A(m4-7,kk0), B reuse; issue B-q2,q3(t+1) ----
        #pragma unroll
        for (int m = 0; m < 4; ++m) af[m] = *(const bf16x8*)&lds[ab + aBase + (m + 4) * 1024 + cx0];
        if (pf) { ISSUE(1, 2, tt + 1, nb); ISSUE(1, 3, tt + 1, nb); }
        fence_bar();
        __builtin_amdgcn_s_setprio(1);
        #pragma unroll
        for (int m = 0; m < 4; ++m)
            #pragma unroll
            for (int n = 0; n < 4; ++n)
                acc[m + 4][n] = __builtin_amdgcn_mfma_f32_16x16x32_bf16(af[m], bfv[n], acc[m + 4][n], 0, 0, 0);
        __builtin_amdgcn_s_setprio(0);
        fence_bar();

        // ---- PH3: A(m0-3,kk1) + B(n0-3,kk1); issue A-q0,q2(t+1) ----
        #pragma unroll
        for (int m = 0; m < 4; ++m) af[m] = *(const bf16x8*)&lds[ab + aBase + m * 1024 + cx1];
        #pragma unroll
        for (int n = 0; n < 4; ++n) bfv[n] = *(const bf16x8*)&lds[ab + bBase + n * 1024 + cx1];
        if (pf) { ISSUE(0, 0, tt + 1, nb); ISSUE(0, 2, tt + 1, nb); }
        fence_bar();
        __builtin_amdgcn_s_setprio(1);
        #pragma unroll
        for (int m = 0; m < 4; ++m)
            #pragma unroll
            for (int n = 0; n < 4; ++n)
                acc[m][n] = __builtin_amdgcn_mfma_f32_16x16x32_bf16(af[m], bfv[n], acc[m][n], 0, 0, 0);
        __builtin_amdgcn_s_setprio(0);
        fence_bar();

        // ---- PH4: A(m4-7,kk1), B reuse; issue A-q1,q3(t+1); vmcnt(2) ----
        #pragma unroll
        for (int m = 0; m < 4; ++m) af[m] = *(const bf16x8*)&lds[ab + aBase + (m + 4) * 1024 + cx1];
        if (pf) {
            ISSUE(0, 1, tt + 1, nb); ISSUE(0, 3, tt + 1, nb);
            asm volatile("s_waitcnt vmcnt(2)" ::: "memory");
        } else {
            asm volatile("s_waitcnt vmcnt(0)" ::: "memory");
        }
        fence_bar();
        __builtin_amdgcn_s_setprio(1);
        #pragma unroll
        for (int m = 0; m < 4; ++m)
            #pragma unroll
            for (int n = 0; n < 4; ++n)
                acc[m + 4][n] = __builtin_amdgcn_mfma_f32_16x16x32_bf16(af[m], bfv[n], acc[m + 4][n], 0, 0, 0);
        __builtin_amdgcn_s_setprio(0);
        fence_bar();
    }
    #undef ISSUE

    // epilogue
    const int lr = (l >> 4) * 4, lc = l & 15;
    #pragma unroll
    for (int m = 0; m < 8; ++m) {
        #pragma unroll
        for (int n = 0; n < 4; ++n) {
            int rr = brow + wr * 128 + m * 16 + lr;
            int cc = bcol + wc * 64 + n * 16 + lc;
            #pragma unroll
            for (int j = 0; j < 4; ++j) {
                if constexpr (OUTV == 0)
                    ((u16*)Cout)[(size_t)blockIdx.z * sC + (size_t)(rr + j) * ldc + cc] = f2bf(acc[m][n][j]);
                else
                    ((float*)Cout)[(size_t)blockIdx.z * sC + (size_t)(rr + j) * ldc + cc] = acc[m][n][j];
            }
        }
    }
}

// ---------------- 2-phase 128x128 GEMM (proven; used for PV) -----------------
template <int OUTV>
__global__ __launch_bounds__(256, 2)
void gemm_bt(const u16* __restrict__ A0, int lda, size_t sA,
             const u16* __restrict__ B0, int ldb, size_t sB,
             void* __restrict__ Cout, int ldc, size_t sC, int kdim) {
    __shared__ u16 lA[128 * 64];
    __shared__ u16 lB[128 * 64];
    const u16* A = A0 + (size_t)blockIdx.z * sA;
    const u16* B = B0 + (size_t)blockIdx.z * sB;
    const int t = threadIdx.x;
    const int w = t >> 6, l = t & 63;
    const int wr = w >> 1, wc = w & 1;
    const int brow = blockIdx.x * 128, bcol = blockIdx.y * 128;
    const int rt = l >> 3;
    const int cb = (l & 7) * 8;

    auto ldsA3 = (__attribute__((address_space(3))) char*)lA;
    auto ldsB3 = (__attribute__((address_space(3))) char*)lB;

    f32x4 acc[4][4];
    #pragma unroll
    for (int m = 0; m < 4; ++m)
        #pragma unroll
        for (int n = 0; n < 4; ++n)
            acc[m][n] = (f32x4){0.f, 0.f, 0.f, 0.f};

    for (int k0 = 0; k0 < kdim; k0 += 64) {
        __syncthreads();
        #pragma unroll
        for (int p = 0; p < 4; ++p) {
            int chunk = p * 4 + w;
            const u16* ga = A + (size_t)(brow + chunk * 8 + rt) * lda + k0 + cb;
            __builtin_amdgcn_global_load_lds(
                (const __attribute__((address_space(1))) void*)ga,
                (__attribute__((address_space(3))) void*)(ldsA3 + chunk * 1024), 16, 0, 0);
            const u16* gb = B + (size_t)(bcol + chunk * 8 + rt) * ldb + k0 + cb;
            __builtin_amdgcn_global_load_lds(
                (const __attribute__((address_space(1))) void*)gb,
                (__attribute__((address_space(3))) void*)(ldsB3 + chunk * 1024), 16, 0, 0);
        }
        __syncthreads();
        #pragma unroll
        for (int kk = 0; kk < 2; ++kk) {
            bf16x8 af[4], bfv[4];
            #pragma unroll
            for (int m = 0; m < 4; ++m)
                af[m] = *(const bf16x8*)&lA[(wr * 64 + m * 16 + (l & 15)) * 64 + kk * 32 + (l >> 4) * 8];
            #pragma unroll
            for (int n = 0; n < 4; ++n)
                bfv[n] = *(const bf16x8*)&lB[(wc * 64 + n * 16 + (l & 15)) * 64 + kk * 32 + (l >> 4) * 8];
            #pragma unroll
            for (int m = 0; m < 4; ++m)
                #pragma unroll
                for (int n = 0; n < 4; ++n)
                    acc[m][n] = __builtin_amdgcn_mfma_f32_16x16x32_bf16(af[m], bfv[n], acc[m][n], 0, 0, 0);
        }
    }

    const int lrow = (l >> 4) * 4, lcol = l & 15;
    #pragma unroll
    for (int m = 0; m < 4; ++m) {
        #pragma unroll
        for (int n = 0; n < 4; ++n) {
            int rr = brow + wr * 64 + m * 16 + lrow;
            int cc = bcol + wc * 64 + n * 16 + lcol;
            #pragma unroll
            for (int j = 0; j < 4; ++j) {
                if constexpr (OUTV == 0)
                    ((u16*)Cout)[(size_t)blockIdx.z * sC + (size_t)(rr + j) * ldc + cc] = f2bf(acc[m][n][j]);
                else
                    ((float*)Cout)[(size_t)blockIdx.z * sC + (size_t)(rr + j) * ldc + cc] = acc[m][n][j];
            }
        }
    }
}

// ---------------- row softmax ------------------------------------------------
__global__ __launch_bounds__(256)
void softmax_rows(const float* __restrict__ S0, size_t sS, u16* __restrict__ P0, size_t sP,
                  const unsigned char* __restrict__ nm, int bbase) {
    const int row = blockIdx.x, t = threadIdx.x;
    const int b = bbase + blockIdx.z;
    const float* S = S0 + (size_t)blockIdx.z * sS;
    u16* dst = P0 + (size_t)blockIdx.z * sP + (size_t)row * 2048;
    if (nm[b * 2048 + row] == 0) {
        ushort4 u = make_ushort4(0x3A00, 0x3A00, 0x3A00, 0x3A00);
        ((ushort4*)dst)[t] = u;
        ((ushort4*)dst)[t + 256] = u;
        return;
    }
    const float4* src = (const float4*)(S + (size_t)row * 2048);
    float4 a = src[t], c = src[t + 256];
    float v[8] = {a.x, a.y, a.z, a.w, c.x, c.y, c.z, c.w};
    float mx = -1e30f;
    #pragma unroll
    for (int i = 0; i < 8; ++i) { v[i] *= 0.03125f; mx = fmaxf(mx, v[i]); }
    #pragma unroll
    for (int o = 32; o > 0; o >>= 1) mx = fmaxf(mx, __shfl_xor(mx, o));
    __shared__ float redm[4], reds[4];
    if ((t & 63) == 0) redm[t >> 6] = mx;
    __syncthreads();
    mx = fmaxf(fmaxf(redm[0], redm[1]), fmaxf(redm[2], redm[3]));
    float s = 0.f;
    #pragma unroll
    for (int i = 0; i < 8; ++i) { v[i] = expf(v[i] - mx); s += v[i]; }
    #pragma unroll
    for (int o = 32; o > 0; o >>= 1) s += __shfl_xor(s, o);
    if ((t & 63) == 0) reds[t >> 6] = s;
    __syncthreads();
    s = (reds[0] + reds[1]) + (reds[2] + reds[3]);
    float inv = 1.0f / s;
    ushort4 o0 = make_ushort4(f2bf(v[0] * inv), f2bf(v[1] * inv), f2bf(v[2] * inv), f2bf(v[3] * inv));
    ushort4 o1 = make_ushort4(f2bf(v[4] * inv), f2bf(v[5] * inv), f2bf(v[6] * inv), f2bf(v[7] * inv));
    ((ushort4*)dst)[t] = o0;
    ((ushort4*)dst)[t + 256] = o1;
}

extern "C" void kernel_launch(void* const* d_in, const int* in_sizes, int n_in,
                              void* d_out, int out_size, void* d_ws, size_t ws_size,
                              hipStream_t stream) {
    const float* x  = (const float*)d_in[0];
    const float* Wq = (const float*)d_in[1];
    const float* Wk = (const float*)d_in[2];
    const float* Wv = (const float*)d_in[3];
    const unsigned int* mask = (const unsigned int*)d_in[4];
    float* out = (float*)d_out;

    char* p = (char*)d_ws;
    u16* Wt  = (u16*)p;  p += (size_t)3072 * 1024 * 2;
    u16* xb  = (u16*)p;  p += (size_t)8192 * 1024 * 2;
    u16* qkv = (u16*)p;  p += (size_t)8192 * 3072 * 2;
    u16* vt  = (u16*)p;  p += (size_t)4 * 1024 * 2048 * 2;
    char* base = p;
    const size_t sizeS = (size_t)2048 * 2048 * 4;
    const size_t sizeP = (size_t)2048 * 2048 * 2;
    bool batched = ws_size >= (size_t)(base - (char*)d_ws) + 4 * (sizeS + sizeP) + 8192;

    float* S = (float*)base;
    u16* P;
    unsigned char* nm;
    if (batched) {
        P  = (u16*)(base + 4 * sizeS);
        nm = (unsigned char*)(base + 4 * (sizeS + sizeP));
    } else {
        P  = (u16*)(base + sizeS);
        nm = (unsigned char*)(base + sizeS + sizeP);
    }

    normMask<<<1, 256, 0, stream>>>(mask, nm);
    transW<<<dim3(16, 16, 3), 256, 0, stream>>>(Wq, Wk, Wv, Wt);
    convX<<<2048, 256, 0, stream>>>(x, xb);
    // QKV: M=8192 N=3072 K=1024 -> 32x12 = 384 tiles
    gemm8p<0><<<dim3(384, 1, 1), 512, 0, stream>>>(
        xb, 1024, 0, Wt, 1024, 0, qkv, 3072, 0, 1024, 12);
    transV<<<dim3(32, 16, 4), 256, 0, stream>>>(qkv, vt);

    if (batched) {
        // scores: per batch 8x8 tiles, z=4 -> 256 blocks = 1/CU
        gemm8p<1><<<dim3(64, 1, 4), 512, 0, stream>>>(
            qkv, 3072, (size_t)2048 * 3072, qkv + 1024, 3072, (size_t)2048 * 3072,
            S, 2048, (size_t)2048 * 2048, 1024, 8);
        softmax_rows<<<dim3(2048, 1, 4), 256, 0, stream>>>(
            S, (size_t)2048 * 2048, P, (size_t)2048 * 2048, nm, 0);
        gemm_bt<2><<<dim3(16, 8, 4), 256, 0, stream>>>(
            P, 2048, (size_t)2048 * 2048, vt, 2048, (size_t)1024 * 2048,
            out, 1024, (size_t)2048 * 1024, 2048);
    } else {
        for (int b = 0; b < 4; ++b) {
            const u16* Qb = qkv + (size_t)b * 2048 * 3072;
            gemm8p<1><<<dim3(64, 1, 1), 512, 0, stream>>>(
                Qb, 3072, 0, Qb + 1024, 3072, 0, S, 2048, 0, 1024, 8);
            softmax_rows<<<dim3(2048, 1, 1), 256, 0, stream>>>(S, 0, P, 0, nm, b);
            gemm_bt<2><<<dim3(16, 8, 1), 256, 0, stream>>>(
                P, 2048, 0, vt + (size_t)b * 1024 * 2048, 2048, 0,
                out + (size_t)b * 2048 * 1024, 1024, 0, 2048);
        }
    }
}